// Round 9
// baseline (36.936 us; speedup 1.0000x reference)
//
#include <hip/hip_runtime.h>

#define CIN 16
#define COUT 32
#define NB 8
#define HW 4096
#define PPW 66                 // padded image width
#define PPA (66 * 66)          // padded pixels per image
#define KF 160                 // features per pixel: 16ch * 10 (silu, T1..T8, zero)
#define NCH 20                 // 16B chunks per pixel (KF/8)

typedef short bf16x8 __attribute__((ext_vector_type(8)));
typedef float f32x16 __attribute__((ext_vector_type(16)));

__device__ inline unsigned short f2bf(float f) {
    unsigned u = __builtin_bit_cast(unsigned, f);
    u += 0x7FFFu + ((u >> 16) & 1u);            // RNE
    return (unsigned short)(u >> 16);
}
__device__ inline unsigned pk(float a, float b) {
    return (unsigned)f2bf(a) | ((unsigned)f2bf(b) << 16);
}

#define FEAT_N4 (16 * 4 * PPA)            // 278784 threads: (b, cg, pp), 4 channels each
#define FB4 ((FEAT_N4 + 255) / 256)       // 1089 blocks
#define WF_N (9 * COUT * KF)              // 46080 = 90 frags * 64 lanes * 8
#define WB ((WF_N + 255) / 256)           // 180 blocks

// ---------- Prep: features chunk-major g2t[b][c][pp][8] + fragment-linear weights ----------
// g2t unchanged from r8. wfl for 32x32x16: frag = shift*10 + st (st = K/16 step);
//   wfl[frag*512 + lane*8 + e] = Wf[shift][o = lane&31][kel = st*16 + (lane>>5)*8 + e]
__global__ __launch_bounds__(256) void kan_prep(const float* __restrict__ x,
                                                const float* __restrict__ w,
                                                const float* __restrict__ c,
                                                unsigned short* __restrict__ g2t,
                                                unsigned short* __restrict__ wfl) {
    if (blockIdx.x < FB4) {
        const int t = blockIdx.x * 256 + threadIdx.x;
        if (t >= FEAT_N4) return;
        const int pp = t % PPA;           // fastest -> coalesced stores
        const int bc = t / PPA;
        const int cg = bc & 3;
        const int b  = bc >> 2;
        const int py = pp / PPW;
        const int px = pp - py * PPW;

        unsigned rw[20];
        const bool interior = (py >= 1) & (py <= 64) & (px >= 1) & (px <= 64);
        if (interior) {
            const int pix = (py - 1) * 64 + (px - 1);
#pragma unroll
            for (int j = 0; j < 4; ++j) {
                const int i = cg * 4 + j;
                const float v  = x[((size_t)(b * CIN + i)) * HW + pix];
                const float p  = __expf(-v);
                const float p2 = p * p;
                const float s  = v * __builtin_amdgcn_rcpf(1.f + p);           // silu
                const float u  = (1.f - p2) * __builtin_amdgcn_rcpf(1.f + p2); // tanh
                const float u2 = 2.f * u;
                const float t1 = u;
                const float t2 = u2 * u - 1.f;
                const float t3 = u2 * t2 - t1;
                const float t4 = u2 * t3 - t2;
                const float t5 = u2 * t4 - t3;
                const float t6 = u2 * t5 - t4;
                const float t7 = u2 * t6 - t5;
                const float t8 = u2 * t7 - t6;
                rw[j * 5 + 0] = pk(s, t1);
                rw[j * 5 + 1] = pk(t2, t3);
                rw[j * 5 + 2] = pk(t4, t5);
                rw[j * 5 + 3] = pk(t6, t7);
                rw[j * 5 + 4] = (unsigned)f2bf(t8);   // hi half 0 (pad feature)
            }
        } else {
#pragma unroll
            for (int j = 0; j < 20; ++j) rw[j] = 0u;
        }
        uint4* dst = (uint4*)g2t;
#pragma unroll
        for (int q = 0; q < 5; ++q)
            dst[((size_t)(b * NCH + cg * 5 + q)) * PPA + pp] =
                make_uint4(rw[4 * q], rw[4 * q + 1], rw[4 * q + 2], rw[4 * q + 3]);
    } else {
        const int t = (blockIdx.x - FB4) * 256 + threadIdx.x;
        if (t >= WF_N) return;
        const int e    = t & 7;
        const int lane = (t >> 3) & 63;
        const int frag = t >> 9;              // 0..89 = shift*10 + st
        const int shift = frag / 10;
        const int st    = frag % 10;
        const int o     = lane & 31;
        const int kel   = st * 16 + (lane >> 5) * 8 + e;
        const int i     = kel / 10, n = kel % 10;
        float val = 0.f;
        if (n != 9) {
            const float wv = w[(size_t)(i * COUT + o) * 9 + shift];
            val = (n == 0) ? wv : wv * c[((size_t)(i * COUT + o) * 9 + shift) * NB + (n - 1)];
        }
        wfl[t] = f2bf(val);
    }
}

// ---------- MFMA GEMM: 32x32x16, one A-read + one B-read + one MFMA per K-step ----------
// Block = 256 thr = 4 waves = 2 rows; wave wv: row y0+(wv>>1), px x0=(wv&1)*32, all 32 cout.
#define P0_FRAGS 50                        // shifts 0-4
#define P1_FRAGS 40                        // shifts 5-8
#define LDSE (P0_FRAGS * 512)              // 25600 bf16 = 51.2 KB

__global__ __launch_bounds__(256, 2) void kan_gemm(const unsigned short* __restrict__ g2t,
                                                   const unsigned short* __restrict__ wfl,
                                                   float* __restrict__ out) {
    __shared__ unsigned short ldsA[LDSE];

    const int bid = blockIdx.x;
    const int blk = ((bid & 7) << 6) | (bid >> 3);   // XCD swizzle: 2 images per XCD
    const int b   = blk >> 5;
    const int tid = threadIdx.x;
    const int l   = tid & 63;
    const int wv  = tid >> 6;
    const int y   = ((blk & 31) << 1) + (wv >> 1);
    const int x0  = (wv & 1) * 32;
    const int colp = l & 31;
    const int hi   = l >> 5;

    const unsigned short* abase = ldsA + l * 8;   // lane-linear A reads (conflict-free)

    f32x16 acc;
#pragma unroll
    for (int r = 0; r < 16; ++r) acc[r] = 0.f;

    // ---- phase 0: shifts 0-4 ----
    for (int ch = tid; ch < P0_FRAGS * 64; ch += 256)
        *(uint4*)&ldsA[ch * 8] = *(const uint4*)&wfl[ch * 8];
    __syncthreads();

#pragma unroll
    for (int ss = 0; ss < 5; ++ss) {
        const int dy = ss / 3 - 1, dx = ss % 3 - 1;
        const int pp = (y + 1 + dy) * PPW + (x0 + colp + 1 + dx);
        // lane reads chunk (st*2 + hi), pixel pp: halves read 512B contiguous each
        const unsigned short* bq = g2t + ((size_t)(b * NCH + hi) * PPA + pp) * 8;
#pragma unroll
        for (int st = 0; st < 10; ++st) {
            const bf16x8 bf = *(const bf16x8*)(bq + (size_t)(st * 2) * PPA * 8);
            const bf16x8 av = *(const bf16x8*)(abase + (ss * 10 + st) * 512);
            acc = __builtin_amdgcn_mfma_f32_32x32x16_bf16(av, bf, acc, 0, 0, 0);
        }
    }
    __syncthreads();

    // ---- phase 1: shifts 5-8 ----
    for (int ch = tid; ch < P1_FRAGS * 64; ch += 256)
        *(uint4*)&ldsA[ch * 8] = *(const uint4*)&wfl[(size_t)P0_FRAGS * 512 + ch * 8];
    __syncthreads();

#pragma unroll
    for (int ss = 0; ss < 4; ++ss) {
        const int shift = 5 + ss;
        const int dy = shift / 3 - 1, dx = shift % 3 - 1;
        const int pp = (y + 1 + dy) * PPW + (x0 + colp + 1 + dx);
        const unsigned short* bq = g2t + ((size_t)(b * NCH + hi) * PPA + pp) * 8;
#pragma unroll
        for (int st = 0; st < 10; ++st) {
            const bf16x8 bf = *(const bf16x8*)(bq + (size_t)(st * 2) * PPA * 8);
            const bf16x8 av = *(const bf16x8*)(abase + (ss * 10 + st) * 512);
            acc = __builtin_amdgcn_mfma_f32_32x32x16_bf16(av, bf, acc, 0, 0, 0);
        }
    }

    // D: col(pixel) = lane&31, row(cout) = (r&3) + 8*(r>>2) + 4*hi
    float* op = out + (size_t)b * COUT * HW + y * 64 + x0 + colp;
#pragma unroll
    for (int r = 0; r < 16; ++r) {
        const int o = (r & 3) + 8 * (r >> 2) + 4 * hi;
        op[(size_t)o * HW] = acc[r];
    }
}

extern "C" void kernel_launch(void* const* d_in, const int* in_sizes, int n_in,
                              void* d_out, int out_size, void* d_ws, size_t ws_size,
                              hipStream_t stream) {
    const float* x = (const float*)d_in[0];
    const float* w = (const float*)d_in[1];
    const float* c = (const float*)d_in[2];
    float* out = (float*)d_out;

    unsigned short* g2t = (unsigned short*)d_ws;                       // 16*20*4356*8 bf16 = 22.3 MB
    unsigned short* wfl = (unsigned short*)((char*)d_ws + (size_t)16 * PPA * KF * 2);

    kan_prep<<<FB4 + WB, 256, 0, stream>>>(x, w, c, g2t, wfl);
    kan_gemm<<<512, 256, 0, stream>>>(g2t, wfl, out);
}